// Round 13
// baseline (147.046 us; speedup 1.0000x reference)
//
#include <hip/hip_runtime.h>
#include <math.h>

typedef __attribute__((ext_vector_type(8))) short short8;
typedef __attribute__((ext_vector_type(4))) short short4v;
typedef __attribute__((ext_vector_type(4))) float f32x4;
typedef __attribute__((ext_vector_type(4))) float float4v;
typedef __attribute__((ext_vector_type(2))) unsigned int uint2v;

__device__ __forceinline__ unsigned short f2bf(float f){   // RNE
  unsigned int u = __float_as_uint(f);
  u += 0x7FFFu + ((u >> 16) & 1u);
  return (unsigned short)(u >> 16);
}
__device__ __forceinline__ float bf2f(short s){
  return __uint_as_float(((unsigned int)(unsigned short)s) << 16);
}
// packed f32x2 -> bf16x2, single HW instr. Used ONLY for P in soft_pv
// (P in [0,1] feeds a normalized average; rounding noise cancels).
__device__ __forceinline__ unsigned int cvtpk(float lo, float hi){
  unsigned int r;
  asm("v_cvt_pk_bf16_f32 %0, %1, %2" : "=v"(r) : "v"(lo), "v"(hi));
  return r;
}

typedef __attribute__((address_space(1))) const unsigned char* gas_t;
typedef __attribute__((address_space(3))) unsigned char* las_t;
__device__ __forceinline__ void async16(const void* g, void* l) {
  __builtin_amdgcn_global_load_lds((gas_t)g, (las_t)l, 16, 0, 0);
}

#define SC2 0.1803368801111204f   /* 0.125 * log2(e); folded into stored q */

// ---------------------------------------------------------------------------
// prep_w: Wt_qkv[n][k] = bf16(W_qkv[k][n]); Wt_out[n][k] = bf16(W_out[k][n])
// ---------------------------------------------------------------------------
__global__ __launch_bounds__(256) void prep_w(
    const float* __restrict__ Wqkv, const float* __restrict__ Wout,
    unsigned short* __restrict__ Wtq, unsigned short* __restrict__ Wto)
{
  int idx = blockIdx.x * 256 + threadIdx.x;
  if (idx < 192 * 512) {
    int n = idx >> 9, k = idx & 511;
    Wtq[idx] = f2bf(Wqkv[k * 192 + n]);
  } else {
    int i2 = idx - 192 * 512;
    int n = i2 >> 6, k = i2 & 63;
    Wto[i2] = f2bf(Wout[k * 512 + n]);
  }
}

// ---------------------------------------------------------------------------
// qkv: x[16384,512]fp32 @ Wt[192,512]bf16 -> q,k [16384,64], vT [4][64][4096]
// grid = 768 = 3 parts x 256 rowblocks. W DOUBLE-buffered in 128-col k-slices
// (2x16 KB): one barrier per slice; stage(s+1) overlaps compute(s). (R12)
// part==0 (q) stored PRE-SCALED by SC2 so attn's exp2 needs no multiply.
// ---------------------------------------------------------------------------
__global__ __launch_bounds__(256) void qkv_kernel(
    const float* __restrict__ x,
    const unsigned short* __restrict__ Wt,
    unsigned short* __restrict__ qg,
    unsigned short* __restrict__ kg,
    unsigned short* __restrict__ vT)
{
  __shared__ __align__(16) unsigned short Wb[2][64][128]; // 32 KB
  __shared__ __align__(16) unsigned short vbuf[64][72];   // 9.2 KB
  const int part = blockIdx.x % 3;
  const int rb   = blockIdx.x / 3;
  const int lane = threadIdx.x & 63;
  const int wave = threadIdx.x >> 6;
  const int mrow = lane & 15;
  const int quad = lane >> 4;
  const int mb = rb * 64;
  const int m0 = mb + wave * 16;
  const int sw = mrow & 7;

  const int srow = lane >> 4;       // 0..3
  const int sch  = lane & 15;       // 0..15
#define STAGE_W(s, dst)                                                       \
  {                                                                           \
    _Pragma("unroll")                                                         \
    for (int ii = 0; ii < 4; ii++) {                                          \
      const int r0 = wave * 16 + ii * 4;                                      \
      const int r  = r0 + srow;                                               \
      const int cd = (sch & 8) | ((sch ^ (r & 7)) & 7);                       \
      async16(Wt + (size_t)(part * 64 + r) * 512 + (s) * 128 + cd * 8,        \
              (dst) + r0 * 128);                                              \
    }                                                                         \
  }

  STAGE_W(0, &Wb[0][0][0])

  f32x4 acc[4];
#pragma unroll
  for (int t = 0; t < 4; t++) acc[t] = (f32x4){0.f, 0.f, 0.f, 0.f};
  const float* xp = x + (size_t)(m0 + mrow) * 512 + quad * 8;

  for (int s = 0; s < 4; s++) {
    __syncthreads();   // slice s landed; compute(s-1) reads done (dbuf safe)
    if (s < 3) STAGE_W(s + 1, &Wb[(s + 1) & 1][0][0])
    const unsigned short* Wc = &Wb[s & 1][0][0];
#pragma unroll
    for (int l = 0; l < 4; l++) {
      const int kk = s * 4 + l;
      float4v a0 = *(const float4v*)(xp + kk * 32);
      float4v a1 = *(const float4v*)(xp + kk * 32 + 4);
      short8 af;
#pragma unroll
      for (int j = 0; j < 4; j++) { af[j] = (short)f2bf(a0[j]); af[4 + j] = (short)f2bf(a1[j]); }
      const int c   = l * 4 + quad;
      const int pos = (c & 8) | ((c ^ sw) & 7);
#pragma unroll
      for (int t = 0; t < 4; t++) {
        short8 bf = *(const short8*)(Wc + (t * 16 + mrow) * 128 + pos * 8);
        acc[t] = __builtin_amdgcn_mfma_f32_16x16x32_bf16(af, bf, acc[t], 0, 0, 0);
      }
    }
  }

  const float osc = (part == 0) ? SC2 : 1.0f;   // fold softmax scale into q
  __syncthreads();
#pragma unroll
  for (int t = 0; t < 4; t++)
#pragma unroll
    for (int r = 0; r < 4; r++)
      vbuf[wave * 16 + quad * 4 + r][t * 16 + mrow] = f2bf(acc[t][r] * osc);
  __syncthreads();

  if (part < 2) {
    unsigned short* dst = part ? kg : qg;
    const int row = threadIdx.x >> 2;
    const int seg = (threadIdx.x & 3) * 16;
    short8 w0 = *(const short8*)&vbuf[row][seg];
    short8 w1 = *(const short8*)&vbuf[row][seg + 8];
    unsigned short* p = dst + (size_t)(mb + row) * 64 + seg;
    *(short8*)(p) = w0;
    *(short8*)(p + 8) = w1;
  } else {
    const int d  = threadIdx.x >> 2;
    const int s8 = (threadIdx.x & 3) * 16;
    const int bb = rb >> 6;
    const int sb = mb & 4095;
    short8 w0, w1;
#pragma unroll
    for (int i = 0; i < 8; i++) {
      w0[i] = (short)vbuf[s8 + i][d];
      w1[i] = (short)vbuf[s8 + 8 + i][d];
    }
    unsigned short* dst = vT + (size_t)bb * (64 * 4096) + (size_t)d * 4096 + sb + s8;
    *(short8*)(dst) = w0;
    *(short8*)(dst + 8) = w1;
  }
#undef STAGE_W
}

// ---------------------------------------------------------------------------
// flash attention, m=0. Split-K chunk=512, BN=64, O^T = V^T @ P^T.
// Block = 256 q rows = 8 waves x 32 q (two 16-row s-slices per wave, 512
// threads). Doubling the q-extent per block HALVES K/V staging volume and
// barrier events per unit MFMA work (K/V tile staged once serves 2x rows).
// s-loop reuses p[16]/pbuf sequentially -> ~same VGPR as the 32-row/wave
// R0 shape (measured 120, 4 waves/SIMD). Tasks/batch = sum((qb>>1)+1, qb<16)
// = 72; grid = 288 -- ALL blocks co-resident (<512 slots at 2 blocks/CU).
// LDS 51.7 KB unchanged. K/V double-buffered, one barrier per k-tile.
// ---------------------------------------------------------------------------
template <bool MASKED>
__device__ __forceinline__ void soft_pv(
    const f32x4* sA, const short8* vf, int kb, int qlane, int quad, int mrow,
    float& lacc, f32x4* o, unsigned short (*pb)[72])
{
  float p[16];
#pragma unroll
  for (int t = 0; t < 4; t++)
#pragma unroll
    for (int r = 0; r < 4; r++) {
      float v = sA[t][r];
      if (MASKED && (kb + t * 16 + quad * 4 + r > qlane)) v = -3.0e38f;
      p[t * 4 + r] = exp2f(v);           // scores pre-scaled by SC2
    }
  float ps = 0.f;
#pragma unroll
  for (int i = 0; i < 16; i++) ps += p[i];
  lacc += ps;
#pragma unroll
  for (int t = 0; t < 4; t++) {
    unsigned int d0 = cvtpk(p[t * 4 + 0], p[t * 4 + 1]);
    unsigned int d1 = cvtpk(p[t * 4 + 2], p[t * 4 + 3]);
    *(uint2v*)&pb[mrow][t * 16 + quad * 4] = (uint2v){d0, d1};
  }
  short8 pf0 = *(const short8*)&pb[mrow][quad * 8];
  short8 pf1 = *(const short8*)&pb[mrow][32 + quad * 8];
#pragma unroll
  for (int c = 0; c < 4; c++) {
    o[c] = __builtin_amdgcn_mfma_f32_16x16x32_bf16(vf[2 * c],     pf0, o[c], 0, 0, 0);
    o[c] = __builtin_amdgcn_mfma_f32_16x16x32_bf16(vf[2 * c + 1], pf1, o[c], 0, 0, 0);
  }
}

__global__ __launch_bounds__(512) void attn_kernel(
    const unsigned short* __restrict__ qg,
    const unsigned short* __restrict__ kg,
    const unsigned short* __restrict__ vT,
    unsigned short* __restrict__ Opart,
    float* __restrict__ lpart)
{
  __shared__ __align__(16) unsigned short Kb[2][64][64];   // 16 KB
  __shared__ __align__(16) unsigned short Vb[2][64][64];   // 16 KB
  __shared__ __align__(16) unsigned short pbuf[8][16][72]; // 18.4 KB
  const int lane = threadIdx.x & 63;
  const int wave = threadIdx.x >> 6;   // 0..7
  const int mrow = lane & 15;
  const int quad = lane >> 4;
  const int sw   = mrow & 7;

  // task decode, heavy tasks (high qb) first; 256-row q-blocks, chunk=512
  int t = 71 - (blockIdx.x % 72);
  const int b = blockIdx.x / 72;
  int qb = 15, c = 0;
  for (int qq = 0; qq < 16; qq++) {
    const int ncq = (qq >> 1) + 1;     // chunks needed by 256-row block qq
    if (t < ncq) { qb = qq; c = t; break; }
    t -= ncq;
  }

  const int sq0w = qb * 256 + wave * 32;   // this wave's 32 q rows (2 slices)
  const int g0w  = b * 4096 + sq0w;

  short8 qf[2][2];
#pragma unroll
  for (int s = 0; s < 2; s++) {
    const unsigned short* qp = qg + (size_t)(g0w + 16 * s + mrow) * 64 + quad * 8;
    qf[s][0] = *(const short8*)(qp);
    qf[s][1] = *(const short8*)(qp + 32);
  }

  const int kstart = c << 9;
  const int qend   = qb * 256 + 256;
  const int kend   = (kstart + 512 < qend) ? (kstart + 512) : qend;
  const int nTb    = (kend - kstart) >> 6;   // both 64-aligned; 1..8

  f32x4 o[2][4];
#pragma unroll
  for (int s = 0; s < 2; s++)
#pragma unroll
    for (int ct = 0; ct < 4; ct++) o[s][ct] = (f32x4){0.f, 0.f, 0.f, 0.f};
  float lr[2] = {0.f, 0.f};

  const unsigned short* kbase = kg + (size_t)b * 4096 * 64;
  const unsigned short* vbase = vT + (size_t)b * 64 * 4096;
  const int shalf = lane >> 3;   // 0..7
  const int sch   = lane & 7;    // 0..7

  // 8 waves x 8 rows: one async16 pair per wave covers the 64-row K/V tile
#define STAGE_KV(kb, Kd, Vd)                                                  \
  {                                                                           \
    const int r0 = wave * 8;                                                  \
    const int r  = r0 + shalf;                                                \
    const int cd = sch ^ (r & 7);                                             \
    async16(kbase + (size_t)((kb) + r) * 64 + cd * 8, (Kd) + r0 * 64);        \
    async16(vbase + (size_t)r * 4096 + (kb) + cd * 8, (Vd) + r0 * 64);        \
  }

  STAGE_KV(kstart, &Kb[0][0][0], &Vb[0][0][0])
  __syncthreads();

  for (int j = 0; j < nTb; j++) {
    const int kb = kstart + 64 * j;
    if (j + 1 < nTb)
      STAGE_KV(kb + 64, &Kb[(j + 1) & 1][0][0], &Vb[(j + 1) & 1][0][0])
    const unsigned short* Kc = &Kb[j & 1][0][0];
    const unsigned short* Vc = &Vb[j & 1][0][0];

    const bool anyact = (kb <= sq0w + 32 - 1);   // any of this wave's rows
    if (anyact) {
      short8 kf[8];
#pragma unroll
      for (int tt = 0; tt < 4; tt++) {
        const unsigned short* kr = Kc + (tt * 16 + mrow) * 64;
        kf[2 * tt]     = *(const short8*)(kr + (quad ^ sw) * 8);
        kf[2 * tt + 1] = *(const short8*)(kr + ((quad + 4) ^ sw) * 8);
      }
      f32x4 sA[2][4];
      bool act[2];
#pragma unroll
      for (int s = 0; s < 2; s++) {
        act[s] = (kb <= sq0w + 16 * s + 15);
        if (act[s]) {
#pragma unroll
          for (int tt = 0; tt < 4; tt++) {
            f32x4 z = (f32x4){0.f, 0.f, 0.f, 0.f};
            z = __builtin_amdgcn_mfma_f32_16x16x32_bf16(kf[2 * tt],     qf[s][0], z, 0, 0, 0);
            z = __builtin_amdgcn_mfma_f32_16x16x32_bf16(kf[2 * tt + 1], qf[s][1], z, 0, 0, 0);
            sA[s][tt] = z;
          }
        }
      }
      short8 vf[8];
#pragma unroll
      for (int cc = 0; cc < 4; cc++) {
        const unsigned short* vr = Vc + (cc * 16 + mrow) * 64;
        vf[2 * cc]     = *(const short8*)(vr + (quad ^ sw) * 8);
        vf[2 * cc + 1] = *(const short8*)(vr + ((quad + 4) ^ sw) * 8);
      }
#pragma unroll
      for (int s = 0; s < 2; s++) {
        if (!act[s]) continue;
        const int qlo = sq0w + 16 * s;
        if (kb + 63 <= qlo)
          soft_pv<false>(sA[s], vf, kb, qlo + mrow, quad, mrow, lr[s], o[s], pbuf[wave]);
        else
          soft_pv<true> (sA[s], vf, kb, qlo + mrow, quad, mrow, lr[s], o[s], pbuf[wave]);
      }
    }
    __syncthreads();
  }
#undef STAGE_KV

  // epilogue: cross-quad l sum; unnormalized O^T partial (bf16, RNE) + l
#pragma unroll
  for (int s = 0; s < 2; s++) {
    float lt = lr[s];
    lt += __shfl_xor(lt, 16);
    lt += __shfl_xor(lt, 32);
    const size_t row = (size_t)c * 16384 + g0w + 16 * s + mrow;
#pragma unroll
    for (int ct = 0; ct < 4; ct++) {
      short4v ob;
#pragma unroll
      for (int r = 0; r < 4; r++) ob[r] = (short)f2bf(o[s][ct][r]);
      *(short4v*)(Opart + row * 64 + ct * 16 + quad * 4) = ob;
    }
    if (quad == 0) lpart[row] = lt;
  }
}

// ---------------------------------------------------------------------------
// combine partials (plain sum, m=0) + fused out-projection + coalesced store.
// grid = 512 = 256 row-blocks x 2 col-halves (R12 proven form).
// nc = 1..8 chunks of 512 keys -- matches attn's chunk coverage exactly.
// ---------------------------------------------------------------------------
__global__ __launch_bounds__(256) void combine_kernel(
    const unsigned short* __restrict__ Opart,
    const float* __restrict__ lpart,
    const unsigned short* __restrict__ WtO,
    const float* __restrict__ bias,
    float* __restrict__ out)
{
  __shared__ __align__(16) unsigned short Wob[256][64];  // 32 KB (2 chunks)
  __shared__ __align__(16) float obuf[4][16][132];       // 33.8 KB
  const int lane = threadIdx.x & 63;
  const int wave = threadIdx.x >> 6;
  const int mrow = lane & 15;
  const int quad = lane >> 4;
  const int rb   = blockIdx.x >> 1;
  const int half = blockIdx.x & 1;         // cols [half*256, half*256+256)
  const int g0 = rb * 64 + wave * 16;
  const int nc = ((g0 & 4095) >> 9) + 1;   // 1..8 chunks of 512 keys

  {
    const int hl  = lane >> 3;
    const int chp = lane & 7;
#pragma unroll
    for (int ii = 0; ii < 8; ii++) {
      const int r0 = wave * 64 + ii * 8;
      const int r  = r0 + hl;
      const int cd = chp ^ (r & 7);
      async16(WtO + (size_t)(half * 256 + r) * 64 + cd * 8, &Wob[r0][0]);
    }
  }

  float L = 0.f;
  f32x4 A0 = (f32x4){0,0,0,0}, A1 = A0, A2 = A0, A3 = A0;
  for (int cI = 0; cI < nc; cI++) {
    const size_t row = (size_t)cI * 16384 + g0 + mrow;
    L += lpart[row];
    const unsigned short* op = Opart + row * 64 + quad * 8;
    short8 x0 = *(const short8*)(op);
    short8 x1 = *(const short8*)(op + 32);
#pragma unroll
    for (int j = 0; j < 4; j++) {
      A0[j] += bf2f(x0[j]); A1[j] += bf2f(x0[4 + j]);
      A2[j] += bf2f(x1[j]); A3[j] += bf2f(x1[4 + j]);
    }
  }
  const float inv = 1.0f / L;
  short8 of0, of1;
#pragma unroll
  for (int i = 0; i < 4; i++) {
    of0[i]     = (short)f2bf(A0[i] * inv);
    of0[i + 4] = (short)f2bf(A1[i] * inv);
    of1[i]     = (short)f2bf(A2[i] * inv);
    of1[i + 4] = (short)f2bf(A3[i] * inv);
  }
  __syncthreads();   // Wob staged (hidden under the gather)

  const int sw = mrow & 7;
  for (int chi = 0; chi < 2; chi++) {
    const int ch = half * 2 + chi;
#pragma unroll
    for (int t = 0; t < 8; t++) {
      const int n = ch * 128 + t * 16 + mrow;
      const unsigned short* wr = &Wob[chi * 128 + t * 16 + mrow][0];
      short8 w0 = *(const short8*)(wr + (quad ^ sw) * 8);
      short8 w1 = *(const short8*)(wr + ((quad + 4) ^ sw) * 8);
      f32x4 pr = (f32x4){0,0,0,0};
      pr = __builtin_amdgcn_mfma_f32_16x16x32_bf16(of0, w0, pr, 0, 0, 0);
      pr = __builtin_amdgcn_mfma_f32_16x16x32_bf16(of1, w1, pr, 0, 0, 0);
      const float bv = bias[n];
#pragma unroll
      for (int r = 0; r < 4; r++)
        obuf[wave][quad * 4 + r][t * 16 + mrow] = pr[r] + bv;
    }
    // wave-local LDS transpose -> coalesced float4 stores (obuf[wave] is
    // wave-private: in-wave write->read ordering, no block barrier needed)
#pragma unroll
    for (int j = 0; j < 4; j++) {
#pragma unroll
      for (int h = 0; h < 2; h++) {
        const int row = 4 * j + (lane >> 4);
        const int col = 4 * (lane & 15) + 64 * h;
        float4v v = *(const float4v*)&obuf[wave][row][col];
        *(float4v*)(out + (size_t)(g0 + row) * 512 + ch * 128 + col) = v;
      }
    }
  }
}

// ---------------------------------------------------------------------------
extern "C" void kernel_launch(void* const* d_in, const int* in_sizes, int n_in,
                              void* d_out, int out_size, void* d_ws, size_t ws_size,
                              hipStream_t stream) {
  const float* x    = (const float*)d_in[0];   // [4,4096,512]
  const float* Wqkv = (const float*)d_in[1];   // [512,192]
  const float* Wout = (const float*)d_in[2];   // [64,512]
  const float* bout = (const float*)d_in[3];   // [512]
  float* out = (float*)d_out;                  // [4,4096,512] fp32

  unsigned short* q   = (unsigned short*)d_ws;       // 2 MB
  unsigned short* k   = q   + 16384 * 64;            // 2 MB
  unsigned short* vT  = k   + 16384 * 64;            // 2 MB
  unsigned short* Wtq = vT  + 4 * 64 * 4096;         // 192 KB
  unsigned short* Wto = Wtq + 192 * 512;             // 64 KB
  unsigned short* Opart = Wto + 512 * 64;            // [8][16384][64] bf16 = 16.8 MB
  float* lprt = (float*)(Opart + (size_t)8 * 16384 * 64);  // [8][16384] = 512 KB
  // total ws: ~23.6 MB (proven budget)

  prep_w<<<512, 256, 0, stream>>>(Wqkv, Wout, Wtq, Wto);
  qkv_kernel<<<768, 256, 0, stream>>>(x, Wtq, q, k, vT);
  attn_kernel<<<288, 512, 0, stream>>>(q, k, vT, Opart, lprt);
  combine_kernel<<<512, 256, 0, stream>>>(Opart, lprt, Wto, bout, out);
}

// Round 14
// 135.704 us; speedup vs baseline: 1.0836x; 1.0836x over previous
//
#include <hip/hip_runtime.h>
#include <math.h>

typedef __attribute__((ext_vector_type(8))) short short8;
typedef __attribute__((ext_vector_type(4))) short short4v;
typedef __attribute__((ext_vector_type(4))) float f32x4;
typedef __attribute__((ext_vector_type(4))) float float4v;
typedef __attribute__((ext_vector_type(2))) unsigned int uint2v;

__device__ __forceinline__ unsigned short f2bf(float f){   // RNE
  unsigned int u = __float_as_uint(f);
  u += 0x7FFFu + ((u >> 16) & 1u);
  return (unsigned short)(u >> 16);
}
__device__ __forceinline__ float bf2f(short s){
  return __uint_as_float(((unsigned int)(unsigned short)s) << 16);
}
// packed f32x2 -> bf16x2, single HW instr. Used ONLY for P in soft_pv
// (P in [0,1] feeds a normalized average; rounding noise cancels).
__device__ __forceinline__ unsigned int cvtpk(float lo, float hi){
  unsigned int r;
  asm("v_cvt_pk_bf16_f32 %0, %1, %2" : "=v"(r) : "v"(lo), "v"(hi));
  return r;
}

typedef __attribute__((address_space(1))) const unsigned char* gas_t;
typedef __attribute__((address_space(3))) unsigned char* las_t;
__device__ __forceinline__ void async16(const void* g, void* l) {
  __builtin_amdgcn_global_load_lds((gas_t)g, (las_t)l, 16, 0, 0);
}

#define SC2 0.1803368801111204f   /* 0.125 * log2(e); folded into stored q */

// ---------------------------------------------------------------------------
// prep_w: Wt_qkv[n][k] = bf16(W_qkv[k][n]); Wt_out[n][k] = bf16(W_out[k][n])
// ---------------------------------------------------------------------------
__global__ __launch_bounds__(256) void prep_w(
    const float* __restrict__ Wqkv, const float* __restrict__ Wout,
    unsigned short* __restrict__ Wtq, unsigned short* __restrict__ Wto)
{
  int idx = blockIdx.x * 256 + threadIdx.x;
  if (idx < 192 * 512) {
    int n = idx >> 9, k = idx & 511;
    Wtq[idx] = f2bf(Wqkv[k * 192 + n]);
  } else {
    int i2 = idx - 192 * 512;
    int n = i2 >> 6, k = i2 & 63;
    Wto[i2] = f2bf(Wout[k * 512 + n]);
  }
}

// ---------------------------------------------------------------------------
// qkv: x[16384,512]fp32 @ Wt[192,512]bf16 -> q,k [16384,64], vT [4][64][4096]
// grid = 768. XCD CO-LOCATION: part = bid>>8, rb = bid&255 -- the 3 part-
// blocks for one row-block are {rb, rb+256, rb+512}, all == rb (mod 8), so
// the round-robin block->XCD map puts them on the SAME XCD: parts 1,2 re-
// read x from the local L2 instead of L3. W DOUBLE-buffered 128-col slices.
// part==0 (q) stored PRE-SCALED by SC2 so attn's exp2 needs no multiply.
// ---------------------------------------------------------------------------
__global__ __launch_bounds__(256) void qkv_kernel(
    const float* __restrict__ x,
    const unsigned short* __restrict__ Wt,
    unsigned short* __restrict__ qg,
    unsigned short* __restrict__ kg,
    unsigned short* __restrict__ vT)
{
  __shared__ __align__(16) unsigned short Wb[2][64][128]; // 32 KB
  __shared__ __align__(16) unsigned short vbuf[64][72];   // 9.2 KB
  const int part = blockIdx.x >> 8;   // 0..2 (triple co-located on one XCD)
  const int rb   = blockIdx.x & 255;
  const int lane = threadIdx.x & 63;
  const int wave = threadIdx.x >> 6;
  const int mrow = lane & 15;
  const int quad = lane >> 4;
  const int mb = rb * 64;
  const int m0 = mb + wave * 16;
  const int sw = mrow & 7;

  const int srow = lane >> 4;       // 0..3
  const int sch  = lane & 15;       // 0..15
#define STAGE_W(s, dst)                                                       \
  {                                                                           \
    _Pragma("unroll")                                                         \
    for (int ii = 0; ii < 4; ii++) {                                          \
      const int r0 = wave * 16 + ii * 4;                                      \
      const int r  = r0 + srow;                                               \
      const int cd = (sch & 8) | ((sch ^ (r & 7)) & 7);                       \
      async16(Wt + (size_t)(part * 64 + r) * 512 + (s) * 128 + cd * 8,        \
              (dst) + r0 * 128);                                              \
    }                                                                         \
  }

  STAGE_W(0, &Wb[0][0][0])

  f32x4 acc[4];
#pragma unroll
  for (int t = 0; t < 4; t++) acc[t] = (f32x4){0.f, 0.f, 0.f, 0.f};
  const float* xp = x + (size_t)(m0 + mrow) * 512 + quad * 8;

  for (int s = 0; s < 4; s++) {
    __syncthreads();   // slice s landed; compute(s-1) reads done (dbuf safe)
    if (s < 3) STAGE_W(s + 1, &Wb[(s + 1) & 1][0][0])
    const unsigned short* Wc = &Wb[s & 1][0][0];
#pragma unroll
    for (int l = 0; l < 4; l++) {
      const int kk = s * 4 + l;
      float4v a0 = *(const float4v*)(xp + kk * 32);
      float4v a1 = *(const float4v*)(xp + kk * 32 + 4);
      short8 af;
#pragma unroll
      for (int j = 0; j < 4; j++) { af[j] = (short)f2bf(a0[j]); af[4 + j] = (short)f2bf(a1[j]); }
      const int c   = l * 4 + quad;
      const int pos = (c & 8) | ((c ^ sw) & 7);
#pragma unroll
      for (int t = 0; t < 4; t++) {
        short8 bf = *(const short8*)(Wc + (t * 16 + mrow) * 128 + pos * 8);
        acc[t] = __builtin_amdgcn_mfma_f32_16x16x32_bf16(af, bf, acc[t], 0, 0, 0);
      }
    }
  }

  const float osc = (part == 0) ? SC2 : 1.0f;   // fold softmax scale into q
  __syncthreads();
#pragma unroll
  for (int t = 0; t < 4; t++)
#pragma unroll
    for (int r = 0; r < 4; r++)
      vbuf[wave * 16 + quad * 4 + r][t * 16 + mrow] = f2bf(acc[t][r] * osc);
  __syncthreads();

  if (part < 2) {
    unsigned short* dst = part ? kg : qg;
    const int row = threadIdx.x >> 2;
    const int seg = (threadIdx.x & 3) * 16;
    short8 w0 = *(const short8*)&vbuf[row][seg];
    short8 w1 = *(const short8*)&vbuf[row][seg + 8];
    unsigned short* p = dst + (size_t)(mb + row) * 64 + seg;
    *(short8*)(p) = w0;
    *(short8*)(p + 8) = w1;
  } else {
    const int d  = threadIdx.x >> 2;
    const int s8 = (threadIdx.x & 3) * 16;
    const int bb = rb >> 6;
    const int sb = mb & 4095;
    short8 w0, w1;
#pragma unroll
    for (int i = 0; i < 8; i++) {
      w0[i] = (short)vbuf[s8 + i][d];
      w1[i] = (short)vbuf[s8 + 8 + i][d];
    }
    unsigned short* dst = vT + (size_t)bb * (64 * 4096) + (size_t)d * 4096 + sb + s8;
    *(short8*)(dst) = w0;
    *(short8*)(dst + 8) = w1;
  }
#undef STAGE_W
}

// ---------------------------------------------------------------------------
// flash attention, m=0. Split-K chunk=512, BN=64, O^T = V^T @ P^T.
// EXACT R12 form (proven 135.5 us): block = 128 q rows = 8 waves x 16 q
// (512 threads); 2 blocks/CU = 16 waves/CU (VGPR cap). R13 lesson: grid 288
// (256-row blocks) drops to ~1.1 blocks/CU -> waves/CU dominates staging
// amortization; keep grid >= 512.
// ---------------------------------------------------------------------------
template <bool MASKED>
__device__ __forceinline__ void soft_pv(
    const f32x4* sA, const short8* vf, int kb, int qlane, int quad, int mrow,
    float& lacc, f32x4* o, unsigned short (*pb)[72])
{
  float p[16];
#pragma unroll
  for (int t = 0; t < 4; t++)
#pragma unroll
    for (int r = 0; r < 4; r++) {
      float v = sA[t][r];
      if (MASKED && (kb + t * 16 + quad * 4 + r > qlane)) v = -3.0e38f;
      p[t * 4 + r] = exp2f(v);           // scores pre-scaled by SC2
    }
  float ps = 0.f;
#pragma unroll
  for (int i = 0; i < 16; i++) ps += p[i];
  lacc += ps;
#pragma unroll
  for (int t = 0; t < 4; t++) {
    unsigned int d0 = cvtpk(p[t * 4 + 0], p[t * 4 + 1]);
    unsigned int d1 = cvtpk(p[t * 4 + 2], p[t * 4 + 3]);
    *(uint2v*)&pb[mrow][t * 16 + quad * 4] = (uint2v){d0, d1};
  }
  short8 pf0 = *(const short8*)&pb[mrow][quad * 8];
  short8 pf1 = *(const short8*)&pb[mrow][32 + quad * 8];
#pragma unroll
  for (int c = 0; c < 4; c++) {
    o[c] = __builtin_amdgcn_mfma_f32_16x16x32_bf16(vf[2 * c],     pf0, o[c], 0, 0, 0);
    o[c] = __builtin_amdgcn_mfma_f32_16x16x32_bf16(vf[2 * c + 1], pf1, o[c], 0, 0, 0);
  }
}

__global__ __launch_bounds__(512) void attn_kernel(
    const unsigned short* __restrict__ qg,
    const unsigned short* __restrict__ kg,
    const unsigned short* __restrict__ vT,
    unsigned short* __restrict__ Opart,
    float* __restrict__ lpart)
{
  __shared__ __align__(16) unsigned short Kb[2][64][64];   // 16 KB
  __shared__ __align__(16) unsigned short Vb[2][64][64];   // 16 KB
  __shared__ __align__(16) unsigned short pbuf[8][16][72]; // 18.4 KB
  const int lane = threadIdx.x & 63;
  const int wave = threadIdx.x >> 6;   // 0..7
  const int mrow = lane & 15;
  const int quad = lane >> 4;
  const int sw   = mrow & 7;

  // task decode, heavy tasks (high qj) first; 128-row q-blocks, chunk=512
  int t = 143 - (blockIdx.x % 144);
  const int b = blockIdx.x / 144;
  int qj = 31, c = 0;
  for (int qq = 0; qq < 32; qq++) {
    const int ncq = (qq >> 2) + 1;     // chunks needed by 128-row block qq
    if (t < ncq) { qj = qq; c = t; break; }
    t -= ncq;
  }

  const int sq0w = qj * 128 + wave * 16;   // this wave's 16 q rows
  const int g0w  = b * 4096 + sq0w;

  short8 qf[2];
  {
    const unsigned short* qp = qg + (size_t)(g0w + mrow) * 64 + quad * 8;
    qf[0] = *(const short8*)(qp);
    qf[1] = *(const short8*)(qp + 32);
  }

  const int kstart = c << 9;
  const int qend   = qj * 128 + 128;
  const int kend   = (kstart + 512 < qend) ? (kstart + 512) : qend;
  const int nTb    = (kend - kstart) >> 6;   // both 64-aligned; 1..8

  f32x4 o[4];
#pragma unroll
  for (int ct = 0; ct < 4; ct++) o[ct] = (f32x4){0.f, 0.f, 0.f, 0.f};
  float lr = 0.f;

  const unsigned short* kbase = kg + (size_t)b * 4096 * 64;
  const unsigned short* vbase = vT + (size_t)b * 64 * 4096;
  const int shalf = lane >> 3;   // 0..7
  const int sch   = lane & 7;    // 0..7

  // 8 waves x 8 rows: one async16 pair per wave covers the 64-row K/V tile
#define STAGE_KV(kb, Kd, Vd)                                                  \
  {                                                                           \
    const int r0 = wave * 8;                                                  \
    const int r  = r0 + shalf;                                                \
    const int cd = sch ^ (r & 7);                                             \
    async16(kbase + (size_t)((kb) + r) * 64 + cd * 8, (Kd) + r0 * 64);        \
    async16(vbase + (size_t)r * 4096 + (kb) + cd * 8, (Vd) + r0 * 64);        \
  }

  STAGE_KV(kstart, &Kb[0][0][0], &Vb[0][0][0])
  __syncthreads();

  for (int j = 0; j < nTb; j++) {
    const int kb = kstart + 64 * j;
    if (j + 1 < nTb)
      STAGE_KV(kb + 64, &Kb[(j + 1) & 1][0][0], &Vb[(j + 1) & 1][0][0])
    const unsigned short* Kc = &Kb[j & 1][0][0];
    const unsigned short* Vc = &Vb[j & 1][0][0];

    const bool act = (kb <= sq0w + 15);
    if (act) {
      short8 kf[8];
#pragma unroll
      for (int tt = 0; tt < 4; tt++) {
        const unsigned short* kr = Kc + (tt * 16 + mrow) * 64;
        kf[2 * tt]     = *(const short8*)(kr + (quad ^ sw) * 8);
        kf[2 * tt + 1] = *(const short8*)(kr + ((quad + 4) ^ sw) * 8);
      }
      f32x4 sA[4];
#pragma unroll
      for (int tt = 0; tt < 4; tt++) {
        f32x4 z = (f32x4){0.f, 0.f, 0.f, 0.f};
        z = __builtin_amdgcn_mfma_f32_16x16x32_bf16(kf[2 * tt],     qf[0], z, 0, 0, 0);
        z = __builtin_amdgcn_mfma_f32_16x16x32_bf16(kf[2 * tt + 1], qf[1], z, 0, 0, 0);
        sA[tt] = z;
      }
      short8 vf[8];
#pragma unroll
      for (int cc = 0; cc < 4; cc++) {
        const unsigned short* vr = Vc + (cc * 16 + mrow) * 64;
        vf[2 * cc]     = *(const short8*)(vr + (quad ^ sw) * 8);
        vf[2 * cc + 1] = *(const short8*)(vr + ((quad + 4) ^ sw) * 8);
      }
      if (kb + 63 <= sq0w)
        soft_pv<false>(sA, vf, kb, sq0w + mrow, quad, mrow, lr, o, pbuf[wave]);
      else
        soft_pv<true> (sA, vf, kb, sq0w + mrow, quad, mrow, lr, o, pbuf[wave]);
    }
    __syncthreads();
  }
#undef STAGE_KV

  // epilogue: cross-quad l sum; unnormalized O^T partial (bf16, RNE) + l
  {
    float lt = lr;
    lt += __shfl_xor(lt, 16);
    lt += __shfl_xor(lt, 32);
    const size_t row = (size_t)c * 16384 + g0w + mrow;
#pragma unroll
    for (int ct = 0; ct < 4; ct++) {
      short4v ob;
#pragma unroll
      for (int r = 0; r < 4; r++) ob[r] = (short)f2bf(o[ct][r]);
      *(short4v*)(Opart + row * 64 + ct * 16 + quad * 4) = ob;
    }
    if (quad == 0) lpart[row] = lt;
  }
}

// ---------------------------------------------------------------------------
// combine partials (plain sum, m=0) + fused out-projection + coalesced store.
// grid = 512. XCD CO-LOCATION: half = bid>>8, rb = bid&255 -- the col-half
// pair {rb, rb+256} == rb (mod 8) lands on the same XCD, so the second
// block's Opart/lpart gather hits the local L2 (was L3). Wob 32 KB staged
// once; obuf wave-private (no extra barriers). LDS 65.8 KB -> 2 blocks/CU.
// ---------------------------------------------------------------------------
__global__ __launch_bounds__(256) void combine_kernel(
    const unsigned short* __restrict__ Opart,
    const float* __restrict__ lpart,
    const unsigned short* __restrict__ WtO,
    const float* __restrict__ bias,
    float* __restrict__ out)
{
  __shared__ __align__(16) unsigned short Wob[256][64];  // 32 KB (2 chunks)
  __shared__ __align__(16) float obuf[4][16][132];       // 33.8 KB
  const int lane = threadIdx.x & 63;
  const int wave = threadIdx.x >> 6;
  const int mrow = lane & 15;
  const int quad = lane >> 4;
  const int half = blockIdx.x >> 8;        // 0..1 (pair co-located on XCD)
  const int rb   = blockIdx.x & 255;
  const int g0 = rb * 64 + wave * 16;
  const int nc = ((g0 & 4095) >> 9) + 1;   // 1..8 chunks of 512 keys

  {
    const int hl  = lane >> 3;
    const int chp = lane & 7;
#pragma unroll
    for (int ii = 0; ii < 8; ii++) {
      const int r0 = wave * 64 + ii * 8;
      const int r  = r0 + hl;
      const int cd = chp ^ (r & 7);
      async16(WtO + (size_t)(half * 256 + r) * 64 + cd * 8, &Wob[r0][0]);
    }
  }

  float L = 0.f;
  f32x4 A0 = (f32x4){0,0,0,0}, A1 = A0, A2 = A0, A3 = A0;
  for (int cI = 0; cI < nc; cI++) {
    const size_t row = (size_t)cI * 16384 + g0 + mrow;
    L += lpart[row];
    const unsigned short* op = Opart + row * 64 + quad * 8;
    short8 x0 = *(const short8*)(op);
    short8 x1 = *(const short8*)(op + 32);
#pragma unroll
    for (int j = 0; j < 4; j++) {
      A0[j] += bf2f(x0[j]); A1[j] += bf2f(x0[4 + j]);
      A2[j] += bf2f(x1[j]); A3[j] += bf2f(x1[4 + j]);
    }
  }
  const float inv = 1.0f / L;
  short8 of0, of1;
#pragma unroll
  for (int i = 0; i < 4; i++) {
    of0[i]     = (short)f2bf(A0[i] * inv);
    of0[i + 4] = (short)f2bf(A1[i] * inv);
    of1[i]     = (short)f2bf(A2[i] * inv);
    of1[i + 4] = (short)f2bf(A3[i] * inv);
  }
  __syncthreads();   // Wob staged (hidden under the gather)

  const int sw = mrow & 7;
  for (int chi = 0; chi < 2; chi++) {
    const int ch = half * 2 + chi;
#pragma unroll
    for (int t = 0; t < 8; t++) {
      const int n = ch * 128 + t * 16 + mrow;
      const unsigned short* wr = &Wob[chi * 128 + t * 16 + mrow][0];
      short8 w0 = *(const short8*)(wr + (quad ^ sw) * 8);
      short8 w1 = *(const short8*)(wr + ((quad + 4) ^ sw) * 8);
      f32x4 pr = (f32x4){0,0,0,0};
      pr = __builtin_amdgcn_mfma_f32_16x16x32_bf16(of0, w0, pr, 0, 0, 0);
      pr = __builtin_amdgcn_mfma_f32_16x16x32_bf16(of1, w1, pr, 0, 0, 0);
      const float bv = bias[n];
#pragma unroll
      for (int r = 0; r < 4; r++)
        obuf[wave][quad * 4 + r][t * 16 + mrow] = pr[r] + bv;
    }
    // wave-local LDS transpose -> coalesced float4 stores (obuf[wave] is
    // wave-private: in-wave write->read ordering, no block barrier needed)
#pragma unroll
    for (int j = 0; j < 4; j++) {
#pragma unroll
      for (int h = 0; h < 2; h++) {
        const int row = 4 * j + (lane >> 4);
        const int col = 4 * (lane & 15) + 64 * h;
        float4v v = *(const float4v*)&obuf[wave][row][col];
        *(float4v*)(out + (size_t)(g0 + row) * 512 + ch * 128 + col) = v;
      }
    }
  }
}

// ---------------------------------------------------------------------------
extern "C" void kernel_launch(void* const* d_in, const int* in_sizes, int n_in,
                              void* d_out, int out_size, void* d_ws, size_t ws_size,
                              hipStream_t stream) {
  const float* x    = (const float*)d_in[0];   // [4,4096,512]
  const float* Wqkv = (const float*)d_in[1];   // [512,192]
  const float* Wout = (const float*)d_in[2];   // [64,512]
  const float* bout = (const float*)d_in[3];   // [512]
  float* out = (float*)d_out;                  // [4,4096,512] fp32

  unsigned short* q   = (unsigned short*)d_ws;       // 2 MB
  unsigned short* k   = q   + 16384 * 64;            // 2 MB
  unsigned short* vT  = k   + 16384 * 64;            // 2 MB
  unsigned short* Wtq = vT  + 4 * 64 * 4096;         // 192 KB
  unsigned short* Wto = Wtq + 192 * 512;             // 64 KB
  unsigned short* Opart = Wto + 512 * 64;            // [8][16384][64] bf16 = 16.8 MB
  float* lprt = (float*)(Opart + (size_t)8 * 16384 * 64);  // [8][16384] = 512 KB
  // total ws: ~23.6 MB (proven budget)

  prep_w<<<512, 256, 0, stream>>>(Wqkv, Wout, Wtq, Wto);
  qkv_kernel<<<768, 256, 0, stream>>>(x, Wtq, q, k, vT);
  attn_kernel<<<576, 512, 0, stream>>>(q, k, vT, Opart, lprt);
  combine_kernel<<<512, 256, 0, stream>>>(Opart, lprt, Wto, bout, out);
}

// Round 15
// 135.340 us; speedup vs baseline: 1.0865x; 1.0027x over previous
//
#include <hip/hip_runtime.h>
#include <math.h>

typedef __attribute__((ext_vector_type(8))) short short8;
typedef __attribute__((ext_vector_type(4))) short short4v;
typedef __attribute__((ext_vector_type(4))) float f32x4;
typedef __attribute__((ext_vector_type(4))) float float4v;
typedef __attribute__((ext_vector_type(2))) unsigned int uint2v;

__device__ __forceinline__ unsigned short f2bf(float f){   // RNE
  unsigned int u = __float_as_uint(f);
  u += 0x7FFFu + ((u >> 16) & 1u);
  return (unsigned short)(u >> 16);
}
__device__ __forceinline__ float bf2f(short s){
  return __uint_as_float(((unsigned int)(unsigned short)s) << 16);
}
// packed f32x2 -> bf16x2, single HW instr. Used ONLY for P in soft_pv
// (P in [0,1] feeds a normalized average; rounding noise cancels).
__device__ __forceinline__ unsigned int cvtpk(float lo, float hi){
  unsigned int r;
  asm("v_cvt_pk_bf16_f32 %0, %1, %2" : "=v"(r) : "v"(lo), "v"(hi));
  return r;
}

typedef __attribute__((address_space(1))) const unsigned char* gas_t;
typedef __attribute__((address_space(3))) unsigned char* las_t;
__device__ __forceinline__ void async16(const void* g, void* l) {
  __builtin_amdgcn_global_load_lds((gas_t)g, (las_t)l, 16, 0, 0);
}

#define SC2 0.1803368801111204f   /* 0.125 * log2(e); folded into stored q */

// ---------------------------------------------------------------------------
// prep_w: Wt_qkv[n][k] = bf16(W_qkv[k][n]); Wt_out[n][k] = bf16(W_out[k][n])
// ---------------------------------------------------------------------------
__global__ __launch_bounds__(256) void prep_w(
    const float* __restrict__ Wqkv, const float* __restrict__ Wout,
    unsigned short* __restrict__ Wtq, unsigned short* __restrict__ Wto)
{
  int idx = blockIdx.x * 256 + threadIdx.x;
  if (idx < 192 * 512) {
    int n = idx >> 9, k = idx & 511;
    Wtq[idx] = f2bf(Wqkv[k * 192 + n]);
  } else {
    int i2 = idx - 192 * 512;
    int n = i2 >> 6, k = i2 & 63;
    Wto[i2] = f2bf(Wout[k * 512 + n]);
  }
}

// ---------------------------------------------------------------------------
// qkv: x[16384,512]fp32 @ Wt[192,512]bf16 -> q,k [16384,64], vT [4][64][4096]
// grid = 768. XCD co-location: part = bid>>8, rb = bid&255 (triple {rb,
// rb+256, rb+512} == rb mod 8 -> same XCD; parts 1,2 re-read x from local
// L2). W DOUBLE-buffered 128-col slices (R12). part==0 (q) stored
// PRE-SCALED by SC2 so attn's exp2 needs no multiply.
// ---------------------------------------------------------------------------
__global__ __launch_bounds__(256) void qkv_kernel(
    const float* __restrict__ x,
    const unsigned short* __restrict__ Wt,
    unsigned short* __restrict__ qg,
    unsigned short* __restrict__ kg,
    unsigned short* __restrict__ vT)
{
  __shared__ __align__(16) unsigned short Wb[2][64][128]; // 32 KB
  __shared__ __align__(16) unsigned short vbuf[64][72];   // 9.2 KB
  const int part = blockIdx.x >> 8;   // 0..2 (triple co-located on one XCD)
  const int rb   = blockIdx.x & 255;
  const int lane = threadIdx.x & 63;
  const int wave = threadIdx.x >> 6;
  const int mrow = lane & 15;
  const int quad = lane >> 4;
  const int mb = rb * 64;
  const int m0 = mb + wave * 16;
  const int sw = mrow & 7;

  const int srow = lane >> 4;       // 0..3
  const int sch  = lane & 15;       // 0..15
#define STAGE_W(s, dst)                                                       \
  {                                                                           \
    _Pragma("unroll")                                                         \
    for (int ii = 0; ii < 4; ii++) {                                          \
      const int r0 = wave * 16 + ii * 4;                                      \
      const int r  = r0 + srow;                                               \
      const int cd = (sch & 8) | ((sch ^ (r & 7)) & 7);                       \
      async16(Wt + (size_t)(part * 64 + r) * 512 + (s) * 128 + cd * 8,        \
              (dst) + r0 * 128);                                              \
    }                                                                         \
  }

  STAGE_W(0, &Wb[0][0][0])

  f32x4 acc[4];
#pragma unroll
  for (int t = 0; t < 4; t++) acc[t] = (f32x4){0.f, 0.f, 0.f, 0.f};
  const float* xp = x + (size_t)(m0 + mrow) * 512 + quad * 8;

  for (int s = 0; s < 4; s++) {
    __syncthreads();   // slice s landed; compute(s-1) reads done (dbuf safe)
    if (s < 3) STAGE_W(s + 1, &Wb[(s + 1) & 1][0][0])
    const unsigned short* Wc = &Wb[s & 1][0][0];
#pragma unroll
    for (int l = 0; l < 4; l++) {
      const int kk = s * 4 + l;
      float4v a0 = *(const float4v*)(xp + kk * 32);
      float4v a1 = *(const float4v*)(xp + kk * 32 + 4);
      short8 af;
#pragma unroll
      for (int j = 0; j < 4; j++) { af[j] = (short)f2bf(a0[j]); af[4 + j] = (short)f2bf(a1[j]); }
      const int c   = l * 4 + quad;
      const int pos = (c & 8) | ((c ^ sw) & 7);
#pragma unroll
      for (int t = 0; t < 4; t++) {
        short8 bf = *(const short8*)(Wc + (t * 16 + mrow) * 128 + pos * 8);
        acc[t] = __builtin_amdgcn_mfma_f32_16x16x32_bf16(af, bf, acc[t], 0, 0, 0);
      }
    }
  }

  const float osc = (part == 0) ? SC2 : 1.0f;   // fold softmax scale into q
  __syncthreads();
#pragma unroll
  for (int t = 0; t < 4; t++)
#pragma unroll
    for (int r = 0; r < 4; r++)
      vbuf[wave * 16 + quad * 4 + r][t * 16 + mrow] = f2bf(acc[t][r] * osc);
  __syncthreads();

  if (part < 2) {
    unsigned short* dst = part ? kg : qg;
    const int row = threadIdx.x >> 2;
    const int seg = (threadIdx.x & 3) * 16;
    short8 w0 = *(const short8*)&vbuf[row][seg];
    short8 w1 = *(const short8*)&vbuf[row][seg + 8];
    unsigned short* p = dst + (size_t)(mb + row) * 64 + seg;
    *(short8*)(p) = w0;
    *(short8*)(p + 8) = w1;
  } else {
    const int d  = threadIdx.x >> 2;
    const int s8 = (threadIdx.x & 3) * 16;
    const int bb = rb >> 6;
    const int sb = mb & 4095;
    short8 w0, w1;
#pragma unroll
    for (int i = 0; i < 8; i++) {
      w0[i] = (short)vbuf[s8 + i][d];
      w1[i] = (short)vbuf[s8 + 8 + i][d];
    }
    unsigned short* dst = vT + (size_t)bb * (64 * 4096) + (size_t)d * 4096 + sb + s8;
    *(short8*)(dst) = w0;
    *(short8*)(dst + 8) = w1;
  }
#undef STAGE_W
}

// ---------------------------------------------------------------------------
// flash attention, m=0. Split-K chunk=512, BN=64, O^T = V^T @ P^T.
// R12 form (proven 135.5 us) + T5 s_setprio: 2 independent blocks/CU run
// phase-shifted (no inter-block sync); setprio(1) during the compute region
// lets the MFMA-issuing block win CU issue arbitration over the other
// block's staging waves (m191 mechanism; m190's null was single-block
// lockstep). Drop to prio 0 before the barrier so staging waves catch up.
// ---------------------------------------------------------------------------
template <bool MASKED>
__device__ __forceinline__ void soft_pv(
    const f32x4* sA, const short8* vf, int kb, int qlane, int quad, int mrow,
    float& lacc, f32x4* o, unsigned short (*pb)[72])
{
  float p[16];
#pragma unroll
  for (int t = 0; t < 4; t++)
#pragma unroll
    for (int r = 0; r < 4; r++) {
      float v = sA[t][r];
      if (MASKED && (kb + t * 16 + quad * 4 + r > qlane)) v = -3.0e38f;
      p[t * 4 + r] = exp2f(v);           // scores pre-scaled by SC2
    }
  float ps = 0.f;
#pragma unroll
  for (int i = 0; i < 16; i++) ps += p[i];
  lacc += ps;
#pragma unroll
  for (int t = 0; t < 4; t++) {
    unsigned int d0 = cvtpk(p[t * 4 + 0], p[t * 4 + 1]);
    unsigned int d1 = cvtpk(p[t * 4 + 2], p[t * 4 + 3]);
    *(uint2v*)&pb[mrow][t * 16 + quad * 4] = (uint2v){d0, d1};
  }
  short8 pf0 = *(const short8*)&pb[mrow][quad * 8];
  short8 pf1 = *(const short8*)&pb[mrow][32 + quad * 8];
#pragma unroll
  for (int c = 0; c < 4; c++) {
    o[c] = __builtin_amdgcn_mfma_f32_16x16x32_bf16(vf[2 * c],     pf0, o[c], 0, 0, 0);
    o[c] = __builtin_amdgcn_mfma_f32_16x16x32_bf16(vf[2 * c + 1], pf1, o[c], 0, 0, 0);
  }
}

__global__ __launch_bounds__(512) void attn_kernel(
    const unsigned short* __restrict__ qg,
    const unsigned short* __restrict__ kg,
    const unsigned short* __restrict__ vT,
    unsigned short* __restrict__ Opart,
    float* __restrict__ lpart)
{
  __shared__ __align__(16) unsigned short Kb[2][64][64];   // 16 KB
  __shared__ __align__(16) unsigned short Vb[2][64][64];   // 16 KB
  __shared__ __align__(16) unsigned short pbuf[8][16][72]; // 18.4 KB
  const int lane = threadIdx.x & 63;
  const int wave = threadIdx.x >> 6;   // 0..7
  const int mrow = lane & 15;
  const int quad = lane >> 4;
  const int sw   = mrow & 7;

  // task decode, heavy tasks (high qj) first; 128-row q-blocks, chunk=512
  int t = 143 - (blockIdx.x % 144);
  const int b = blockIdx.x / 144;
  int qj = 31, c = 0;
  for (int qq = 0; qq < 32; qq++) {
    const int ncq = (qq >> 2) + 1;     // chunks needed by 128-row block qq
    if (t < ncq) { qj = qq; c = t; break; }
    t -= ncq;
  }

  const int sq0w = qj * 128 + wave * 16;   // this wave's 16 q rows
  const int g0w  = b * 4096 + sq0w;

  short8 qf[2];
  {
    const unsigned short* qp = qg + (size_t)(g0w + mrow) * 64 + quad * 8;
    qf[0] = *(const short8*)(qp);
    qf[1] = *(const short8*)(qp + 32);
  }

  const int kstart = c << 9;
  const int qend   = qj * 128 + 128;
  const int kend   = (kstart + 512 < qend) ? (kstart + 512) : qend;
  const int nTb    = (kend - kstart) >> 6;   // both 64-aligned; 1..8

  f32x4 o[4];
#pragma unroll
  for (int ct = 0; ct < 4; ct++) o[ct] = (f32x4){0.f, 0.f, 0.f, 0.f};
  float lr = 0.f;

  const unsigned short* kbase = kg + (size_t)b * 4096 * 64;
  const unsigned short* vbase = vT + (size_t)b * 64 * 4096;
  const int shalf = lane >> 3;   // 0..7
  const int sch   = lane & 7;    // 0..7

  // 8 waves x 8 rows: one async16 pair per wave covers the 64-row K/V tile
#define STAGE_KV(kb, Kd, Vd)                                                  \
  {                                                                           \
    const int r0 = wave * 8;                                                  \
    const int r  = r0 + shalf;                                                \
    const int cd = sch ^ (r & 7);                                             \
    async16(kbase + (size_t)((kb) + r) * 64 + cd * 8, (Kd) + r0 * 64);        \
    async16(vbase + (size_t)r * 4096 + (kb) + cd * 8, (Vd) + r0 * 64);        \
  }

  STAGE_KV(kstart, &Kb[0][0][0], &Vb[0][0][0])
  __syncthreads();

  for (int j = 0; j < nTb; j++) {
    const int kb = kstart + 64 * j;
    if (j + 1 < nTb)
      STAGE_KV(kb + 64, &Kb[(j + 1) & 1][0][0], &Vb[(j + 1) & 1][0][0])
    const unsigned short* Kc = &Kb[j & 1][0][0];
    const unsigned short* Vc = &Vb[j & 1][0][0];

    const bool act = (kb <= sq0w + 15);
    if (act) {
      __builtin_amdgcn_s_setprio(1);   // T5: favor compute-phase block
      short8 kf[8];
#pragma unroll
      for (int tt = 0; tt < 4; tt++) {
        const unsigned short* kr = Kc + (tt * 16 + mrow) * 64;
        kf[2 * tt]     = *(const short8*)(kr + (quad ^ sw) * 8);
        kf[2 * tt + 1] = *(const short8*)(kr + ((quad + 4) ^ sw) * 8);
      }
      f32x4 sA[4];
#pragma unroll
      for (int tt = 0; tt < 4; tt++) {
        f32x4 z = (f32x4){0.f, 0.f, 0.f, 0.f};
        z = __builtin_amdgcn_mfma_f32_16x16x32_bf16(kf[2 * tt],     qf[0], z, 0, 0, 0);
        z = __builtin_amdgcn_mfma_f32_16x16x32_bf16(kf[2 * tt + 1], qf[1], z, 0, 0, 0);
        sA[tt] = z;
      }
      short8 vf[8];
#pragma unroll
      for (int cc = 0; cc < 4; cc++) {
        const unsigned short* vr = Vc + (cc * 16 + mrow) * 64;
        vf[2 * cc]     = *(const short8*)(vr + (quad ^ sw) * 8);
        vf[2 * cc + 1] = *(const short8*)(vr + ((quad + 4) ^ sw) * 8);
      }
      if (kb + 63 <= sq0w)
        soft_pv<false>(sA, vf, kb, sq0w + mrow, quad, mrow, lr, o, pbuf[wave]);
      else
        soft_pv<true> (sA, vf, kb, sq0w + mrow, quad, mrow, lr, o, pbuf[wave]);
      __builtin_amdgcn_s_setprio(0);   // let staging waves catch up
    }
    __syncthreads();
  }
#undef STAGE_KV

  // epilogue: cross-quad l sum; unnormalized O^T partial (bf16, RNE) + l
  {
    float lt = lr;
    lt += __shfl_xor(lt, 16);
    lt += __shfl_xor(lt, 32);
    const size_t row = (size_t)c * 16384 + g0w + mrow;
#pragma unroll
    for (int ct = 0; ct < 4; ct++) {
      short4v ob;
#pragma unroll
      for (int r = 0; r < 4; r++) ob[r] = (short)f2bf(o[ct][r]);
      *(short4v*)(Opart + row * 64 + ct * 16 + quad * 4) = ob;
    }
    if (quad == 0) lpart[row] = lt;
  }
}

// ---------------------------------------------------------------------------
// combine partials (plain sum, m=0) + fused out-projection + coalesced store.
// grid = 512. XCD co-location: half = bid>>8, rb = bid&255 (pair {rb,rb+256}
// same XCD -> second gather L2-hot). Wob 32 KB staged once; obuf wave-
// private (no extra barriers). LDS 65.8 KB -> 2 blocks/CU.
// ---------------------------------------------------------------------------
__global__ __launch_bounds__(256) void combine_kernel(
    const unsigned short* __restrict__ Opart,
    const float* __restrict__ lpart,
    const unsigned short* __restrict__ WtO,
    const float* __restrict__ bias,
    float* __restrict__ out)
{
  __shared__ __align__(16) unsigned short Wob[256][64];  // 32 KB (2 chunks)
  __shared__ __align__(16) float obuf[4][16][132];       // 33.8 KB
  const int lane = threadIdx.x & 63;
  const int wave = threadIdx.x >> 6;
  const int mrow = lane & 15;
  const int quad = lane >> 4;
  const int half = blockIdx.x >> 8;        // 0..1 (pair co-located on XCD)
  const int rb   = blockIdx.x & 255;
  const int g0 = rb * 64 + wave * 16;
  const int nc = ((g0 & 4095) >> 9) + 1;   // 1..8 chunks of 512 keys

  {
    const int hl  = lane >> 3;
    const int chp = lane & 7;
#pragma unroll
    for (int ii = 0; ii < 8; ii++) {
      const int r0 = wave * 64 + ii * 8;
      const int r  = r0 + hl;
      const int cd = chp ^ (r & 7);
      async16(WtO + (size_t)(half * 256 + r) * 64 + cd * 8, &Wob[r0][0]);
    }
  }

  float L = 0.f;
  f32x4 A0 = (f32x4){0,0,0,0}, A1 = A0, A2 = A0, A3 = A0;
  for (int cI = 0; cI < nc; cI++) {
    const size_t row = (size_t)cI * 16384 + g0 + mrow;
    L += lpart[row];
    const unsigned short* op = Opart + row * 64 + quad * 8;
    short8 x0 = *(const short8*)(op);
    short8 x1 = *(const short8*)(op + 32);
#pragma unroll
    for (int j = 0; j < 4; j++) {
      A0[j] += bf2f(x0[j]); A1[j] += bf2f(x0[4 + j]);
      A2[j] += bf2f(x1[j]); A3[j] += bf2f(x1[4 + j]);
    }
  }
  const float inv = 1.0f / L;
  short8 of0, of1;
#pragma unroll
  for (int i = 0; i < 4; i++) {
    of0[i]     = (short)f2bf(A0[i] * inv);
    of0[i + 4] = (short)f2bf(A1[i] * inv);
    of1[i]     = (short)f2bf(A2[i] * inv);
    of1[i + 4] = (short)f2bf(A3[i] * inv);
  }
  __syncthreads();   // Wob staged (hidden under the gather)

  const int sw = mrow & 7;
  for (int chi = 0; chi < 2; chi++) {
    const int ch = half * 2 + chi;
#pragma unroll
    for (int t = 0; t < 8; t++) {
      const int n = ch * 128 + t * 16 + mrow;
      const unsigned short* wr = &Wob[chi * 128 + t * 16 + mrow][0];
      short8 w0 = *(const short8*)(wr + (quad ^ sw) * 8);
      short8 w1 = *(const short8*)(wr + ((quad + 4) ^ sw) * 8);
      f32x4 pr = (f32x4){0,0,0,0};
      pr = __builtin_amdgcn_mfma_f32_16x16x32_bf16(of0, w0, pr, 0, 0, 0);
      pr = __builtin_amdgcn_mfma_f32_16x16x32_bf16(of1, w1, pr, 0, 0, 0);
      const float bv = bias[n];
#pragma unroll
      for (int r = 0; r < 4; r++)
        obuf[wave][quad * 4 + r][t * 16 + mrow] = pr[r] + bv;
    }
    // wave-local LDS transpose -> coalesced float4 stores (obuf[wave] is
    // wave-private: in-wave write->read ordering, no block barrier needed)
#pragma unroll
    for (int j = 0; j < 4; j++) {
#pragma unroll
      for (int h = 0; h < 2; h++) {
        const int row = 4 * j + (lane >> 4);
        const int col = 4 * (lane & 15) + 64 * h;
        float4v v = *(const float4v*)&obuf[wave][row][col];
        *(float4v*)(out + (size_t)(g0 + row) * 512 + ch * 128 + col) = v;
      }
    }
  }
}

// ---------------------------------------------------------------------------
extern "C" void kernel_launch(void* const* d_in, const int* in_sizes, int n_in,
                              void* d_out, int out_size, void* d_ws, size_t ws_size,
                              hipStream_t stream) {
  const float* x    = (const float*)d_in[0];   // [4,4096,512]
  const float* Wqkv = (const float*)d_in[1];   // [512,192]
  const float* Wout = (const float*)d_in[2];   // [64,512]
  const float* bout = (const float*)d_in[3];   // [512]
  float* out = (float*)d_out;                  // [4,4096,512] fp32

  unsigned short* q   = (unsigned short*)d_ws;       // 2 MB
  unsigned short* k   = q   + 16384 * 64;            // 2 MB
  unsigned short* vT  = k   + 16384 * 64;            // 2 MB
  unsigned short* Wtq = vT  + 4 * 64 * 4096;         // 192 KB
  unsigned short* Wto = Wtq + 192 * 512;             // 64 KB
  unsigned short* Opart = Wto + 512 * 64;            // [8][16384][64] bf16 = 16.8 MB
  float* lprt = (float*)(Opart + (size_t)8 * 16384 * 64);  // [8][16384] = 512 KB
  // total ws: ~23.6 MB (proven budget)

  prep_w<<<512, 256, 0, stream>>>(Wqkv, Wout, Wtq, Wto);
  qkv_kernel<<<768, 256, 0, stream>>>(x, Wtq, q, k, vT);
  attn_kernel<<<576, 512, 0, stream>>>(q, k, vT, Opart, lprt);
  combine_kernel<<<512, 256, 0, stream>>>(Opart, lprt, Wto, bout, out);
}